// Round 1
// baseline (361.349 us; speedup 1.0000x reference)
//
#include <hip/hip_runtime.h>
#include <math.h>

typedef __attribute__((ext_vector_type(4))) float  floatx4;
typedef __attribute__((ext_vector_type(8))) short  shortx8;
typedef unsigned short ushort_t;
typedef unsigned int   uint32;

#define BB 16
#define LL 4096
#define DD 512
#define SS 64
#define NTOK (BB*LL)       // 65536
#define NCH 64             // scan chunks per sequence (64 tokens each)

// ---------- helpers ----------
__device__ __forceinline__ ushort_t f2bf(float f) {
    uint32 u = __float_as_uint(f);
    u += 0x7FFFu + ((u >> 16) & 1u);   // round-to-nearest-even
    return (ushort_t)(u >> 16);
}
__device__ __forceinline__ float bf2f(ushort_t u) {
    return __uint_as_float(((uint32)u) << 16);
}

// async global->LDS, 16B per lane. lptr must be wave-uniform; HW adds lane*16.
__device__ __forceinline__ void gload16(const void* g, void* l) {
    __builtin_amdgcn_global_load_lds(
        (const __attribute__((address_space(1))) unsigned int*)g,
        (__attribute__((address_space(3))) unsigned int*)l, 16, 0, 0);
}

// ---------- K0: weight conversion ----------
__global__ __launch_bounds__(256) void k_prep(
    const float* __restrict__ Wdt, const float* __restrict__ WB,
    const float* __restrict__ WC,  const float* __restrict__ Wx,
    const float* __restrict__ Wout,
    ushort_t* __restrict__ wcat, ushort_t* __restrict__ woutb)
{
    int tid = blockIdx.x * 256 + threadIdx.x;      // 0..131071
    int n = tid >> 9, k = tid & 511;
    const float* src = (n < 64) ? Wdt : (n < 128) ? WB : (n < 192) ? WC : Wx;
    wcat[tid] = f2bf(src[(n & 63) * 512 + k]);
    if (tid < 512 * 64) woutb[tid] = f2bf(Wout[tid]);
}

// ---------- K1: LayerNorm -> xn bf16 (pure memory-bound) ----------
// one wave per token: 64 lanes x 8 f32
__global__ __launch_bounds__(256) void k_ln(
    const float* __restrict__ x, const float* __restrict__ lnw, const float* __restrict__ lnb,
    ushort_t* __restrict__ xn)
{
    const int wave = threadIdx.x >> 6, lane = threadIdx.x & 63;
    const int tok = blockIdx.x * 4 + wave;
    const float4* xr = (const float4*)(x + (size_t)tok * DD);
    float4 a = xr[lane * 2], b = xr[lane * 2 + 1];
    float s = a.x + a.y + a.z + a.w + b.x + b.y + b.z + b.w;
    float q = a.x*a.x + a.y*a.y + a.z*a.z + a.w*a.w
            + b.x*b.x + b.y*b.y + b.z*b.z + b.w*b.w;
    #pragma unroll
    for (int off = 32; off > 0; off >>= 1) {
        s += __shfl_xor(s, off);
        q += __shfl_xor(q, off);
    }
    float mu = s * (1.0f / 512.0f);
    float rs = rsqrtf(q * (1.0f / 512.0f) - mu * mu + 1e-5f);
    float4 wa = ((const float4*)lnw)[lane * 2], wb = ((const float4*)lnw)[lane * 2 + 1];
    float4 ba = ((const float4*)lnb)[lane * 2], bb = ((const float4*)lnb)[lane * 2 + 1];
    uint4 pk;
    pk.x = (uint32)f2bf((a.x - mu) * rs * wa.x + ba.x) | ((uint32)f2bf((a.y - mu) * rs * wa.y + ba.y) << 16);
    pk.y = (uint32)f2bf((a.z - mu) * rs * wa.z + ba.z) | ((uint32)f2bf((a.w - mu) * rs * wa.w + ba.w) << 16);
    pk.z = (uint32)f2bf((b.x - mu) * rs * wb.x + bb.x) | ((uint32)f2bf((b.y - mu) * rs * wb.y + bb.y) << 16);
    pk.w = (uint32)f2bf((b.z - mu) * rs * wb.z + bb.z) | ((uint32)f2bf((b.w - mu) * rs * wb.w + bb.w) << 16);
    ((uint4*)(xn + (size_t)tok * DD))[lane] = pk;
}

// ---------- K2: projection GEMM 128x256 K=512 (m97-style) + elementwise + chunk summaries ----------
// 512 thr (8 waves). wave w: mh=w>>2 (64-token half = scan chunk), nq=w&3.
// n-tiling n = nt*64 + nq*16 + ln  -> per-lane epilogue holds all 4 projections for s=nq*16+ln.
// LDS XOR swizzle: element (row, k8) at byte row*128 + ((k8 ^ (row&7))<<4)
__global__ __launch_bounds__(512, 4) void k_proj(
    const ushort_t* __restrict__ xn, const ushort_t* __restrict__ wcat,
    const float* __restrict__ bdt, const float* __restrict__ bx_, const float* __restrict__ A_log,
    float* __restrict__ Ap, float* __restrict__ BXv, ushort_t* __restrict__ Ctb,
    float* __restrict__ Asum, float* __restrict__ Bsum)
{
    __shared__ __align__(16) char sBuf[49152];
    ushort_t* sA = (ushort_t*)sBuf;              // swizzled [128][64]
    ushort_t* sB = (ushort_t*)(sBuf + 16384);    // swizzled [256][64]
    float*    sPA = (float*)sBuf;                // [2 ch][64 s][17] alias post-GEMM
    float*    sPB = sPA + 2 * 64 * 17;

    const int tid  = threadIdx.x;
    const int wave = tid >> 6, lane = tid & 63;
    const int ln   = lane & 15, qd = lane >> 4;
    const int mh   = wave >> 2, nq = wave & 3;
    const int token0 = blockIdx.x * 128;

    // precompute swizzled staging source coords
    int tA[2], cA[2], tB[4], cB[4];
    #pragma unroll
    for (int r = 0; r < 2; r++) { int sl = r * 512 + tid; tA[r] = sl >> 3; cA[r] = ((sl & 7) ^ (tA[r] & 7)) * 8; }
    #pragma unroll
    for (int r = 0; r < 4; r++) { int sl = r * 512 + tid; tB[r] = sl >> 3; cB[r] = ((sl & 7) ^ (tB[r] & 7)) * 8; }

    floatx4 acc[4][4] = {};

    for (int kc = 0; kc < 8; kc++) {
        const int kb = kc * 64;
        #pragma unroll
        for (int r = 0; r < 2; r++)
            gload16(xn + (size_t)(token0 + tA[r]) * DD + kb + cA[r],
                    sBuf + r * 8192 + wave * 1024);
        #pragma unroll
        for (int r = 0; r < 4; r++)
            gload16(wcat + (size_t)tB[r] * DD + kb + cB[r],
                    sBuf + 16384 + r * 8192 + wave * 1024);
        __syncthreads();
        #pragma unroll
        for (int ks8 = 0; ks8 < 8; ks8 += 4) {
            shortx8 af[4], bf[4];
            #pragma unroll
            for (int mt = 0; mt < 4; mt++) {
                int t = mh * 64 + mt * 16 + ln;
                af[mt] = *(const shortx8*)&sA[t * 64 + (((ks8 + qd) ^ (ln & 7)) << 3)];
            }
            #pragma unroll
            for (int nt = 0; nt < 4; nt++) {
                int n = nt * 64 + nq * 16 + ln;
                bf[nt] = *(const shortx8*)&sB[n * 64 + (((ks8 + qd) ^ (ln & 7)) << 3)];
            }
            #pragma unroll
            for (int mt = 0; mt < 4; mt++)
                #pragma unroll
                for (int nt = 0; nt < 4; nt++)
                    acc[mt][nt] = __builtin_amdgcn_mfma_f32_16x16x32_bf16(
                        af[mt], bf[nt], acc[mt][nt], 0, 0, 0);
        }
        __syncthreads();
    }

    // ---- per-lane elementwise + segment affine partials ----
    {
        const int s = nq * 16 + ln;
        float bdt_s = bdt[s], bx_s = bx_[s];
        float A_s = -expf(A_log[s]);
        const bool fc = ((blockIdx.x & 31) == 0) && (mh == 0);   // first chunk of sequence
        #pragma unroll
        for (int mt = 0; mt < 4; mt++) {
            float Al = 1.f, Bl = 0.f;
            #pragma unroll
            for (int r = 0; r < 4; r++) {
                int tl  = mt * 16 + qd * 4 + r;            // token within chunk
                int tok = token0 + mh * 64 + tl;
                float zdt = acc[mt][0][r];
                float zb  = acc[mt][1][r];
                float zc  = acc[mt][2][r];
                float zx  = acc[mt][3][r];
                float zin = zdt + bdt_s;
                float sp  = fmaxf(zin, 0.0f) + log1pf(expf(-fabsf(zin)));   // softplus
                float delta = sp * 0.01f + 1e-4f;
                float dA    = fminf(fmaxf(delta * A_s, -10.0f), -1e-4f);
                float a     = fminf(fmaxf(expf(dA), 0.001f), 0.999f) + 1e-10f;
                float bxv   = delta * zb * (zx + bx_s);
                size_t g = (size_t)tok * 64 + s;
                Ap[g] = a; BXv[g] = bxv; Ctb[g] = f2bf(zc);
                bool first = fc && (tl == 0);
                float alpha = first ? 0.f : a;
                float beta  = first ? bxv : a * bxv;
                Al *= alpha;
                Bl = fmaf(alpha, Bl, beta);
            }
            sPA[(mh * 64 + s) * 17 + mt * 4 + qd] = Al;
            sPB[(mh * 64 + s) * 17 + mt * 4 + qd] = Bl;
        }
    }
    __syncthreads();
    if (tid < 128) {   // fold 16 segments -> chunk summary (2 chunks per block)
        int ch = tid >> 6, ss = tid & 63;
        const float* pa = &sPA[(ch * 64 + ss) * 17];
        const float* pb = &sPB[(ch * 64 + ss) * 17];
        float A = pa[0], B = pb[0];
        #pragma unroll
        for (int g = 1; g < 16; g++) {
            A *= pa[g];
            B = fmaf(pa[g], B, pb[g]);
        }
        int o = (blockIdx.x * 2 + ch) * 64 + ss;
        Asum[o] = A; Bsum[o] = B;
    }
}

// ---------- K3: chunk-prefix fold + scan replay -> P bf16 ----------
// block: 256 thr (4 waves = 4 consecutive chunks of one sequence)
__global__ __launch_bounds__(256) void k_scan(
    const float* __restrict__ Ap, const float* __restrict__ BXv, const ushort_t* __restrict__ Ctb,
    const float* __restrict__ Asum, const float* __restrict__ Bsum,
    ushort_t* __restrict__ P)
{
    __shared__ float sAs[4096], sBs[4096];
    const int tid = threadIdx.x;
    const int b = blockIdx.x >> 4, cq = blockIdx.x & 15;
    #pragma unroll
    for (int i = 0; i < 16; i++) {
        int idx = i * 256 + tid;
        sAs[idx] = Asum[b * 4096 + idx];
        sBs[idx] = Bsum[b * 4096 + idx];
    }
    __syncthreads();
    const int w = tid >> 6, s = tid & 63;
    const int c = cq * 4 + w;
    float h = 0.f;
    for (int cc = 0; cc < c; cc++)                 // wave-uniform trip count
        h = fmaf(sAs[cc * 64 + s], h, sBs[cc * 64 + s]);
    size_t base = ((size_t)b * LL + c * 64) * 64 + s;
    const bool fc = (c == 0);
    #pragma unroll 8
    for (int t = 0; t < 64; t++) {
        float a = Ap[base + (size_t)t * 64];
        float v = BXv[base + (size_t)t * 64];
        float alpha = (fc && t == 0) ? 0.f : a;
        float beta  = (fc && t == 0) ? v   : a * v;
        h = fmaf(alpha, h, beta);
        P[base + (size_t)t * 64] = f2bf(bf2f(Ctb[base + (size_t)t * 64]) * h);
    }
}

// ---------- K4: out = P @ Wout^T + bout + clip(Dp)*x ----------
// 256 thr (4 waves), tile 64 tok x 512 d (both halves per block, P staged ONCE), K=64
__global__ __launch_bounds__(256, 4) void k_gemm2(
    const ushort_t* __restrict__ P, const ushort_t* __restrict__ woutb,
    const float* __restrict__ bout, const float* __restrict__ Dp,
    const float* __restrict__ x, float* __restrict__ out)
{
    __shared__ __align__(16) char sPBuf[8192];       // swizzled [64][64] bf16
    __shared__ __align__(16) float sOut[16 * 260];   // f32 epilogue staging (separate: sP survives)
    ushort_t* sP = (ushort_t*)sPBuf;

    const int tid  = threadIdx.x;
    const int wave = tid >> 6, lane = tid & 63;
    const int ln   = lane & 15, qd = lane >> 4;
    const int nq   = wave;
    const int token0 = blockIdx.x * 64;

    // stage P tile (swizzled, async) -- once per block, reused for both d-halves
    #pragma unroll
    for (int r = 0; r < 2; r++) {
        int sl = r * 256 + tid;
        int t = sl >> 3, k8 = (sl & 7) ^ (t & 7);
        gload16(P + (size_t)(token0 + t) * 64 + k8 * 8,
                sPBuf + r * 4096 + wave * 1024);
    }
    __syncthreads();

    #pragma unroll
    for (int half = 0; half < 2; half++) {
        const int nh = half * 256;
        floatx4 acc[4][4] = {};
        #pragma unroll
        for (int ks8 = 0; ks8 < 8; ks8 += 4) {
            shortx8 af[4], bf[4];
            #pragma unroll
            for (int mt = 0; mt < 4; mt++) {
                int t = mt * 16 + ln;
                af[mt] = *(const shortx8*)&sP[t * 64 + (((ks8 + qd) ^ (ln & 7)) << 3)];
            }
            #pragma unroll
            for (int nt = 0; nt < 4; nt++) {
                int d = nh + nq * 64 + nt * 16 + ln;
                bf[nt] = *(const shortx8*)(woutb + (size_t)d * 64 + (ks8 + qd) * 8);
            }
            #pragma unroll
            for (int mt = 0; mt < 4; mt++)
                #pragma unroll
                for (int nt = 0; nt < 4; nt++)
                    acc[mt][nt] = __builtin_amdgcn_mfma_f32_16x16x32_bf16(
                        af[mt], bf[nt], acc[mt][nt], 0, 0, 0);
        }

        // transposed epilogue, float4 coalesced
        for (int mt = 0; mt < 4; mt++) {
            __syncthreads();                      // WAR guard on sOut
            #pragma unroll
            for (int nt = 0; nt < 4; nt++)
                #pragma unroll
                for (int r = 0; r < 4; r++)
                    sOut[(qd * 4 + r) * 260 + nq * 64 + nt * 16 + ln] = acc[mt][nt][r];
            __syncthreads();
            #pragma unroll
            for (int i = 0; i < 4; i++) {
                int idx = i * 256 + tid;
                int row = idx >> 6, c4 = (idx & 63) * 4;
                int tok = token0 + mt * 16 + row;
                int d   = nh + c4;
                float4 o  = *(float4*)&sOut[row * 260 + c4];
                float4 xv = *(const float4*)(x + (size_t)tok * DD + d);
                float4 bo = *(const float4*)(bout + d);
                float4 dp = *(const float4*)(Dp + d);
                float4 res;
                res.x = fmaf(fminf(fmaxf(dp.x, -2.f), 2.f), xv.x, o.x + bo.x);
                res.y = fmaf(fminf(fmaxf(dp.y, -2.f), 2.f), xv.y, o.y + bo.y);
                res.z = fmaf(fminf(fmaxf(dp.z, -2.f), 2.f), xv.z, o.z + bo.z);
                res.w = fmaf(fminf(fmaxf(dp.w, -2.f), 2.f), xv.w, o.w + bo.w);
                *(float4*)(out + (size_t)tok * DD + d) = res;
            }
        }
    }
}

// ---------- launch ----------
extern "C" void kernel_launch(void* const* d_in, const int* in_sizes, int n_in,
                              void* d_out, int out_size, void* d_ws, size_t ws_size,
                              hipStream_t stream)
{
    const float* x     = (const float*)d_in[0];
    const float* lnw   = (const float*)d_in[1];
    const float* lnb   = (const float*)d_in[2];
    const float* Wx    = (const float*)d_in[3];
    const float* bx_   = (const float*)d_in[4];
    const float* Wdt   = (const float*)d_in[5];
    const float* bdt   = (const float*)d_in[6];
    const float* A_log = (const float*)d_in[7];
    const float* WB    = (const float*)d_in[8];
    const float* WC    = (const float*)d_in[9];
    const float* Dp    = (const float*)d_in[10];
    const float* Wout  = (const float*)d_in[11];
    const float* bout  = (const float*)d_in[12];
    float* out = (float*)d_out;

    char* w = (char*)d_ws;
    constexpr size_t SZ_XN = (size_t)NTOK * DD * 2;      // 67.1 MB bf16 x_norm
    constexpr size_t SZ_T  = (size_t)NTOK * 64 * 4;      // 16.8 MB per (tok,s) f32
    ushort_t* xn    = (ushort_t*)(w);
    ushort_t* Pm    = (ushort_t*)(w);                    // alias: P live after xn dead
    float*    Ap    = (float*)(w + SZ_XN);
    float*    BXv   = (float*)(w + SZ_XN + SZ_T);
    ushort_t* Ctb   = (ushort_t*)(w + SZ_XN + 2 * SZ_T); // bf16 now (uses half the slot)
    float*    Asum  = (float*)(w + SZ_XN + 3 * SZ_T);
    float*    Bsum  = (float*)(w + SZ_XN + 3 * SZ_T + 262144);
    ushort_t* Wcat  = (ushort_t*)(w + SZ_XN + 3 * SZ_T + 2 * 262144);
    ushort_t* WoutB = (ushort_t*)(w + SZ_XN + 3 * SZ_T + 2 * 262144 + 262144);

    k_prep<<<512, 256, 0, stream>>>(Wdt, WB, WC, Wx, Wout, Wcat, WoutB);
    k_ln<<<NTOK / 4, 256, 0, stream>>>(x, lnw, lnb, xn);
    k_proj<<<NTOK / 128, 512, 0, stream>>>(xn, Wcat, bdt, bx_, A_log,
                                           Ap, BXv, Ctb, Asum, Bsum);
    k_scan<<<BB * 16, 256, 0, stream>>>(Ap, BXv, Ctb, Asum, Bsum, Pm);
    k_gemm2<<<NTOK / 64, 256, 0, stream>>>(Pm, WoutB, bout, Dp, x, out);
}

// Round 2
// 343.424 us; speedup vs baseline: 1.0522x; 1.0522x over previous
//
#include <hip/hip_runtime.h>
#include <hip/hip_bf16.h>
#include <math.h>

typedef __attribute__((ext_vector_type(4))) float  floatx4;
typedef __attribute__((ext_vector_type(8))) short  shortx8;
typedef unsigned short ushort_t;
typedef unsigned int   uint32;

#define BB 16
#define LL 4096
#define DD 512
#define SS 64
#define NTOK (BB*LL)       // 65536
#define NCH 64             // scan chunks per sequence (64 tokens each)

// ---------- helpers ----------
__device__ __forceinline__ ushort_t f2bf(float f) {
    uint32 u = __float_as_uint(f);
    u += 0x7FFFu + ((u >> 16) & 1u);   // round-to-nearest-even
    return (ushort_t)(u >> 16);
}
__device__ __forceinline__ float bf2f(ushort_t u) {
    return __uint_as_float(((uint32)u) << 16);
}
// packed RNE f32x2 -> bf16x2 (low = first arg)
__device__ __forceinline__ uint32 pack2(float lo, float hi) {
    __hip_bfloat162 h = __float22bfloat162_rn(make_float2(lo, hi));
    union { __hip_bfloat162 h; uint32 u; } cv; cv.h = h;
    return cv.u;
}

// async global->LDS, 16B per lane. lptr must be wave-uniform; HW adds lane*16.
__device__ __forceinline__ void gload16(const void* g, void* l) {
    __builtin_amdgcn_global_load_lds(
        (const __attribute__((address_space(1))) unsigned int*)g,
        (__attribute__((address_space(3))) unsigned int*)l, 16, 0, 0);
}

// ---------- K0: weight prep ----------
// blocks 0..63: wave per row n of wcat' = W * ln_w (bf16) + u[n]=sum(W*ln_w), c[n]=sum(W*ln_b)
// blocks 64..79: Wout -> bf16
__global__ __launch_bounds__(256) void k_prep(
    const float* __restrict__ Wdt, const float* __restrict__ WB,
    const float* __restrict__ WC,  const float* __restrict__ Wx,
    const float* __restrict__ Wout,
    const float* __restrict__ lnw, const float* __restrict__ lnb,
    ushort_t* __restrict__ wcat, ushort_t* __restrict__ woutb,
    float* __restrict__ u, float* __restrict__ c)
{
    const int bid = blockIdx.x;
    if (bid < 64) {
        const int wave = threadIdx.x >> 6, lane = threadIdx.x & 63;
        const int n = bid * 4 + wave;
        const float* src = (n < 64) ? Wdt : (n < 128) ? WB : (n < 192) ? WC : Wx;
        const float* row = src + (size_t)(n & 63) * 512;
        float4 a  = *(const float4*)(row + lane * 8);
        float4 b  = *(const float4*)(row + lane * 8 + 4);
        float4 wa = *(const float4*)(lnw + lane * 8);
        float4 wb = *(const float4*)(lnw + lane * 8 + 4);
        float4 ba = *(const float4*)(lnb + lane * 8);
        float4 bb = *(const float4*)(lnb + lane * 8 + 4);
        float w0 = a.x * wa.x, w1 = a.y * wa.y, w2 = a.z * wa.z, w3 = a.w * wa.w;
        float w4 = b.x * wb.x, w5 = b.y * wb.y, w6 = b.z * wb.z, w7 = b.w * wb.w;
        float us = w0 + w1 + w2 + w3 + w4 + w5 + w6 + w7;
        float cs = a.x*ba.x + a.y*ba.y + a.z*ba.z + a.w*ba.w
                 + b.x*bb.x + b.y*bb.y + b.z*bb.z + b.w*bb.w;
        uint4 o;
        o.x = (uint32)f2bf(w0) | ((uint32)f2bf(w1) << 16);
        o.y = (uint32)f2bf(w2) | ((uint32)f2bf(w3) << 16);
        o.z = (uint32)f2bf(w4) | ((uint32)f2bf(w5) << 16);
        o.w = (uint32)f2bf(w6) | ((uint32)f2bf(w7) << 16);
        ((uint4*)(wcat + (size_t)n * 512))[lane] = o;
        #pragma unroll
        for (int off = 32; off > 0; off >>= 1) {
            us += __shfl_xor(us, off);
            cs += __shfl_xor(cs, off);
        }
        if (lane == 0) { u[n] = us; c[n] = cs; }
    } else {
        int idx = (bid - 64) * 2048 + threadIdx.x * 8;   // 16 blocks cover 32768
        float4 a = *(const float4*)(Wout + idx);
        float4 b = *(const float4*)(Wout + idx + 4);
        uint4 o;
        o.x = (uint32)f2bf(a.x) | ((uint32)f2bf(a.y) << 16);
        o.y = (uint32)f2bf(a.z) | ((uint32)f2bf(a.w) << 16);
        o.z = (uint32)f2bf(b.x) | ((uint32)f2bf(b.y) << 16);
        o.w = (uint32)f2bf(b.z) | ((uint32)f2bf(b.w) << 16);
        *(uint4*)(woutb + idx) = o;
    }
}

// ---------- K1: fused LN + projection GEMM 128x256 K=512 + elementwise + chunk summaries ----------
// Raw x staged as bf16 (reg path, packed converts); LN applied algebraically in epilogue:
//   z = rs_t * (G - mu_t * u_n) + c_n    with G = x @ (ln_w ⊙ W)^T
// Stats (mu, rs) accumulated during staging, 8-lane shuffle reduce after K-loop.
__global__ __launch_bounds__(512, 4) void k_proj(
    const float* __restrict__ x, const ushort_t* __restrict__ wcat,
    const float* __restrict__ u, const float* __restrict__ c,
    const float* __restrict__ bdt, const float* __restrict__ bx_, const float* __restrict__ A_log,
    float* __restrict__ Ap, float* __restrict__ BXv, ushort_t* __restrict__ Ctb,
    float* __restrict__ Asum, float* __restrict__ Bsum)
{
    __shared__ __align__(16) char sBuf[49152];
    __shared__ float sMu[128], sRs[128];
    ushort_t* sA = (ushort_t*)sBuf;              // swizzled [128][64]
    ushort_t* sB = (ushort_t*)(sBuf + 16384);    // swizzled [256][64]
    float*    sPA = (float*)sBuf;                // [2 ch][64 s][17] alias post-GEMM
    float*    sPB = sPA + 2 * 64 * 17;

    const int tid  = threadIdx.x;
    const int wave = tid >> 6, lane = tid & 63;
    const int ln   = lane & 15, qd = lane >> 4;
    const int mh   = wave >> 2, nq = wave & 3;
    const int token0 = blockIdx.x * 128;

    // swizzled staging coords for B (weights, async gload)
    int tB[4], cB[4];
    #pragma unroll
    for (int r = 0; r < 4; r++) { int sl = r * 512 + tid; tB[r] = sl >> 3; cB[r] = ((sl & 7) ^ (tB[r] & 7)) * 8; }
    // A staging slots: sl = r*512+tid -> row = sl>>3 (token), k8 = sl&7 (granule)
    int rowA[2], k8A[2];
    #pragma unroll
    for (int r = 0; r < 2; r++) { int sl = r * 512 + tid; rowA[r] = sl >> 3; k8A[r] = sl & 7; }

    floatx4 acc[4][4] = {};
    float sacc[2] = {0.f, 0.f}, qacc[2] = {0.f, 0.f};

    for (int kc = 0; kc < 8; kc++) {
        const int kb = kc * 64;
        // B tile: async global->LDS (pre-swizzled source)
        #pragma unroll
        for (int r = 0; r < 4; r++)
            gload16(wcat + (size_t)tB[r] * DD + kb + cB[r],
                    sBuf + 16384 + r * 8192 + wave * 1024);
        // A tile: reg-stage raw x -> bf16, swizzled ds_write, accumulate LN stats
        #pragma unroll
        for (int r = 0; r < 2; r++) {
            const float4* xp = (const float4*)(x + (size_t)(token0 + rowA[r]) * DD + kb + k8A[r] * 8);
            float4 v0 = xp[0], v1 = xp[1];
            sacc[r] += (v0.x + v0.y) + (v0.z + v0.w) + (v1.x + v1.y) + (v1.z + v1.w);
            qacc[r] += v0.x*v0.x + v0.y*v0.y + v0.z*v0.z + v0.w*v0.w
                     + v1.x*v1.x + v1.y*v1.y + v1.z*v1.z + v1.w*v1.w;
            uint4 pk;
            pk.x = pack2(v0.x, v0.y);
            pk.y = pack2(v0.z, v0.w);
            pk.z = pack2(v1.x, v1.y);
            pk.w = pack2(v1.z, v1.w);
            *(uint4*)(sBuf + rowA[r] * 128 + ((k8A[r] ^ (rowA[r] & 7)) << 4)) = pk;
        }
        __syncthreads();
        #pragma unroll
        for (int ks8 = 0; ks8 < 8; ks8 += 4) {
            shortx8 af[4], bf[4];
            #pragma unroll
            for (int mt = 0; mt < 4; mt++) {
                int t = mh * 64 + mt * 16 + ln;
                af[mt] = *(const shortx8*)&sA[t * 64 + (((ks8 + qd) ^ (ln & 7)) << 3)];
            }
            #pragma unroll
            for (int nt = 0; nt < 4; nt++) {
                int n = nt * 64 + nq * 16 + ln;
                bf[nt] = *(const shortx8*)&sB[n * 64 + (((ks8 + qd) ^ (ln & 7)) << 3)];
            }
            #pragma unroll
            for (int mt = 0; mt < 4; mt++)
                #pragma unroll
                for (int nt = 0; nt < 4; nt++)
                    acc[mt][nt] = __builtin_amdgcn_mfma_f32_16x16x32_bf16(
                        af[mt], bf[nt], acc[mt][nt], 0, 0, 0);
        }
        __syncthreads();
    }

    // ---- finalize LN stats: 8-lane groups share a token row ----
    #pragma unroll
    for (int r = 0; r < 2; r++) {
        float s_ = sacc[r], q_ = qacc[r];
        s_ += __shfl_xor(s_, 1); q_ += __shfl_xor(q_, 1);
        s_ += __shfl_xor(s_, 2); q_ += __shfl_xor(q_, 2);
        s_ += __shfl_xor(s_, 4); q_ += __shfl_xor(q_, 4);
        if ((lane & 7) == 0) {
            int row = r * 64 + wave * 8 + (lane >> 3);
            float mu = s_ * (1.0f / 512.0f);
            sMu[row] = mu;
            sRs[row] = rsqrtf(q_ * (1.0f / 512.0f) - mu * mu + 1e-5f);
        }
    }
    __syncthreads();

    // ---- per-lane elementwise + segment affine partials ----
    {
        const int s = nq * 16 + ln;
        float bdt_s = bdt[s], bx_s = bx_[s];
        float A_s = -expf(A_log[s]);
        float u0 = u[s], u1 = u[64 + s], u2 = u[128 + s], u3 = u[192 + s];
        float c0 = c[s], c1 = c[64 + s], c2 = c[128 + s], c3 = c[192 + s];
        const bool fc = ((blockIdx.x & 31) == 0) && (mh == 0);   // first chunk of sequence
        #pragma unroll
        for (int mt = 0; mt < 4; mt++) {
            float Al = 1.f, Bl = 0.f;
            #pragma unroll
            for (int r = 0; r < 4; r++) {
                int tl  = mt * 16 + qd * 4 + r;            // token within chunk
                int tok = token0 + mh * 64 + tl;
                float mu_t = sMu[mh * 64 + tl], rs_t = sRs[mh * 64 + tl];
                float zdt = rs_t * (acc[mt][0][r] - mu_t * u0) + c0;
                float zb  = rs_t * (acc[mt][1][r] - mu_t * u1) + c1;
                float zc  = rs_t * (acc[mt][2][r] - mu_t * u2) + c2;
                float zx  = rs_t * (acc[mt][3][r] - mu_t * u3) + c3;
                float zin = zdt + bdt_s;
                float sp  = fmaxf(zin, 0.0f) + log1pf(expf(-fabsf(zin)));   // softplus
                float delta = sp * 0.01f + 1e-4f;
                float dA    = fminf(fmaxf(delta * A_s, -10.0f), -1e-4f);
                float a     = fminf(fmaxf(expf(dA), 0.001f), 0.999f) + 1e-10f;
                float bxv   = delta * zb * (zx + bx_s);
                size_t g = (size_t)tok * 64 + s;
                Ap[g] = a; BXv[g] = bxv; Ctb[g] = f2bf(zc);
                bool first = fc && (tl == 0);
                float alpha = first ? 0.f : a;
                float beta  = first ? bxv : a * bxv;
                Al *= alpha;
                Bl = fmaf(alpha, Bl, beta);
            }
            sPA[(mh * 64 + s) * 17 + mt * 4 + qd] = Al;
            sPB[(mh * 64 + s) * 17 + mt * 4 + qd] = Bl;
        }
    }
    __syncthreads();
    if (tid < 128) {   // fold 16 segments -> chunk summary (2 chunks per block)
        int ch = tid >> 6, ss = tid & 63;
        const float* pa = &sPA[(ch * 64 + ss) * 17];
        const float* pb = &sPB[(ch * 64 + ss) * 17];
        float A = pa[0], B = pb[0];
        #pragma unroll
        for (int g = 1; g < 16; g++) {
            A *= pa[g];
            B = fmaf(pa[g], B, pb[g]);
        }
        int o = (blockIdx.x * 2 + ch) * 64 + ss;
        Asum[o] = A; Bsum[o] = B;
    }
}

// ---------- K3: chunk-prefix fold + scan replay -> P bf16 ----------
// block: 256 thr (4 waves = 4 consecutive chunks of one sequence)
__global__ __launch_bounds__(256) void k_scan(
    const float* __restrict__ Ap, const float* __restrict__ BXv, const ushort_t* __restrict__ Ctb,
    const float* __restrict__ Asum, const float* __restrict__ Bsum,
    ushort_t* __restrict__ P)
{
    __shared__ float sAs[4096], sBs[4096];
    const int tid = threadIdx.x;
    const int b = blockIdx.x >> 4, cq = blockIdx.x & 15;
    #pragma unroll
    for (int i = 0; i < 16; i++) {
        int idx = i * 256 + tid;
        sAs[idx] = Asum[b * 4096 + idx];
        sBs[idx] = Bsum[b * 4096 + idx];
    }
    __syncthreads();
    const int w = tid >> 6, s = tid & 63;
    const int c = cq * 4 + w;
    float h = 0.f;
    for (int cc = 0; cc < c; cc++)                 // wave-uniform trip count
        h = fmaf(sAs[cc * 64 + s], h, sBs[cc * 64 + s]);
    size_t base = ((size_t)b * LL + c * 64) * 64 + s;
    const bool fc = (c == 0);
    #pragma unroll 8
    for (int t = 0; t < 64; t++) {
        float a = Ap[base + (size_t)t * 64];
        float v = BXv[base + (size_t)t * 64];
        float alpha = (fc && t == 0) ? 0.f : a;
        float beta  = (fc && t == 0) ? v   : a * v;
        h = fmaf(alpha, h, beta);
        P[base + (size_t)t * 64] = f2bf(bf2f(Ctb[base + (size_t)t * 64]) * h);
    }
}

// ---------- K4: out = P @ Wout^T + bout + clip(Dp)*x ----------
// 256 thr (4 waves), tile 64 tok x 512 d (both halves per block, P staged ONCE), K=64
__global__ __launch_bounds__(256, 4) void k_gemm2(
    const ushort_t* __restrict__ P, const ushort_t* __restrict__ woutb,
    const float* __restrict__ bout, const float* __restrict__ Dp,
    const float* __restrict__ x, float* __restrict__ out)
{
    __shared__ __align__(16) char sPBuf[8192];       // swizzled [64][64] bf16
    __shared__ __align__(16) float sOut[16 * 260];   // f32 epilogue staging (separate: sP survives)
    ushort_t* sP = (ushort_t*)sPBuf;

    const int tid  = threadIdx.x;
    const int wave = tid >> 6, lane = tid & 63;
    const int ln   = lane & 15, qd = lane >> 4;
    const int nq   = wave;
    const int token0 = blockIdx.x * 64;

    // stage P tile (swizzled, async) -- once per block, reused for both d-halves
    #pragma unroll
    for (int r = 0; r < 2; r++) {
        int sl = r * 256 + tid;
        int t = sl >> 3, k8 = (sl & 7) ^ (t & 7);
        gload16(P + (size_t)(token0 + t) * 64 + k8 * 8,
                sPBuf + r * 4096 + wave * 1024);
    }
    __syncthreads();

    #pragma unroll
    for (int half = 0; half < 2; half++) {
        const int nh = half * 256;
        floatx4 acc[4][4] = {};
        #pragma unroll
        for (int ks8 = 0; ks8 < 8; ks8 += 4) {
            shortx8 af[4], bf[4];
            #pragma unroll
            for (int mt = 0; mt < 4; mt++) {
                int t = mt * 16 + ln;
                af[mt] = *(const shortx8*)&sP[t * 64 + (((ks8 + qd) ^ (ln & 7)) << 3)];
            }
            #pragma unroll
            for (int nt = 0; nt < 4; nt++) {
                int d = nh + nq * 64 + nt * 16 + ln;
                bf[nt] = *(const shortx8*)(woutb + (size_t)d * 64 + (ks8 + qd) * 8);
            }
            #pragma unroll
            for (int mt = 0; mt < 4; mt++)
                #pragma unroll
                for (int nt = 0; nt < 4; nt++)
                    acc[mt][nt] = __builtin_amdgcn_mfma_f32_16x16x32_bf16(
                        af[mt], bf[nt], acc[mt][nt], 0, 0, 0);
        }

        // transposed epilogue, float4 coalesced
        for (int mt = 0; mt < 4; mt++) {
            __syncthreads();                      // WAR guard on sOut
            #pragma unroll
            for (int nt = 0; nt < 4; nt++)
                #pragma unroll
                for (int r = 0; r < 4; r++)
                    sOut[(qd * 4 + r) * 260 + nq * 64 + nt * 16 + ln] = acc[mt][nt][r];
            __syncthreads();
            #pragma unroll
            for (int i = 0; i < 4; i++) {
                int idx = i * 256 + tid;
                int row = idx >> 6, c4 = (idx & 63) * 4;
                int tok = token0 + mt * 16 + row;
                int d   = nh + c4;
                float4 o  = *(float4*)&sOut[row * 260 + c4];
                float4 xv = *(const float4*)(x + (size_t)tok * DD + d);
                float4 bo = *(const float4*)(bout + d);
                float4 dp = *(const float4*)(Dp + d);
                float4 res;
                res.x = fmaf(fminf(fmaxf(dp.x, -2.f), 2.f), xv.x, o.x + bo.x);
                res.y = fmaf(fminf(fmaxf(dp.y, -2.f), 2.f), xv.y, o.y + bo.y);
                res.z = fmaf(fminf(fmaxf(dp.z, -2.f), 2.f), xv.z, o.z + bo.z);
                res.w = fmaf(fminf(fmaxf(dp.w, -2.f), 2.f), xv.w, o.w + bo.w);
                *(float4*)(out + (size_t)tok * DD + d) = res;
            }
        }
    }
}

// ---------- launch ----------
extern "C" void kernel_launch(void* const* d_in, const int* in_sizes, int n_in,
                              void* d_out, int out_size, void* d_ws, size_t ws_size,
                              hipStream_t stream)
{
    const float* x     = (const float*)d_in[0];
    const float* lnw   = (const float*)d_in[1];
    const float* lnb   = (const float*)d_in[2];
    const float* Wx    = (const float*)d_in[3];
    const float* bx_   = (const float*)d_in[4];
    const float* Wdt   = (const float*)d_in[5];
    const float* bdt   = (const float*)d_in[6];
    const float* A_log = (const float*)d_in[7];
    const float* WB    = (const float*)d_in[8];
    const float* WC    = (const float*)d_in[9];
    const float* Dp    = (const float*)d_in[10];
    const float* Wout  = (const float*)d_in[11];
    const float* bout  = (const float*)d_in[12];
    float* out = (float*)d_out;

    char* w = (char*)d_ws;
    constexpr size_t SZ_XN = (size_t)NTOK * DD * 2;      // 67.1 MB region (P lives here)
    constexpr size_t SZ_T  = (size_t)NTOK * 64 * 4;      // 16.8 MB per (tok,s) f32
    ushort_t* Pm    = (ushort_t*)(w);
    float*    Ap    = (float*)(w + SZ_XN);
    float*    BXv   = (float*)(w + SZ_XN + SZ_T);
    ushort_t* Ctb   = (ushort_t*)(w + SZ_XN + 2 * SZ_T); // bf16 (uses half the slot)
    float*    Asum  = (float*)(w + SZ_XN + 3 * SZ_T);
    float*    Bsum  = (float*)(w + SZ_XN + 3 * SZ_T + 262144);
    ushort_t* Wcat  = (ushort_t*)(w + SZ_XN + 3 * SZ_T + 2 * 262144);
    ushort_t* WoutB = (ushort_t*)(w + SZ_XN + 3 * SZ_T + 2 * 262144 + 262144);
    float*    Uc    = (float*)(w + SZ_XN + 3 * SZ_T + 2 * 262144 + 262144 + 65536);
    float*    Cc    = Uc + 256;

    k_prep<<<80, 256, 0, stream>>>(Wdt, WB, WC, Wx, Wout, lnw, lnb, Wcat, WoutB, Uc, Cc);
    k_proj<<<NTOK / 128, 512, 0, stream>>>(x, Wcat, Uc, Cc, bdt, bx_, A_log,
                                           Ap, BXv, Ctb, Asum, Bsum);
    k_scan<<<BB * 16, 256, 0, stream>>>(Ap, BXv, Ctb, Asum, Bsum, Pm);
    k_gemm2<<<NTOK / 64, 256, 0, stream>>>(Pm, WoutB, bout, Dp, x, out);
}